// Round 8
// baseline (4799.097 us; speedup 1.0000x reference)
//
#include <hip/hip_runtime.h>

// ---------------- problem constants ----------------
#define HND    233
#define NL     6
#define GPL    8              // WGs per layer
#define UPW    32             // units per WG (8*32 = 256 >= 233)
#define ROWS   128            // gate rows per WG
#define TSTEPS 16
#define FSTEPS 96
#define NSLOT  (TSTEPS*FSTEPS)
#define CDIM   12
#define G4H    (4*HND)        // 932
#define HP     240            // preferred hout row stride (floats)
#define VINW   496            // vin stream buffer: [x 240 | h 240 | pad 16]
#define NTICK  (6*95+15+1)    // 586 wavefront ticks
#define NHEAD  3
#define BLOCK  512
#define NWORD  234            // u64 words per stream (117 x + 117 h)
#define AG     __HIP_MEMORY_SCOPE_AGENT
#define SENT   0x7FBADBADu    // NaN pattern: unreachable by real data (backstop)

typedef unsigned long long u64;

__device__ __forceinline__ float sigf(float x) { return 1.f / (1.f + expf(-x)); }
__device__ __forceinline__ bool rdy(u64 v) {
  return ((unsigned)v != SENT) && ((unsigned)(v >> 32) != SENT);
}

// Re-poison hout (backstop sentinel) + zero canaries.
__global__ void init_kernel(unsigned* __restrict__ hout, int* __restrict__ cny, int hp) {
  size_t i = (size_t)blockIdx.x * blockDim.x + threadIdx.x;
  size_t stride = (size_t)gridDim.x * blockDim.x;
  const size_t nh = (size_t)NL * NSLOT * hp;
  for (size_t k = i; k < nh; k += stride) hout[k] = ((int)(k % hp) < HND) ? SENT : 0u;
  for (size_t k = i; k < (size_t)NL * NSLOT * GPL; k += stride) cny[k] = 0;
}

// grid: NL*GPL layer WGs + NHEAD head WGs, 512 threads each.
// Wavefront: layer l processes slot (f,t) at loop tick m = 6f+t; <=3 streams.
// Exchange: producers fire relaxed data stores then a per-producer canary
// (no vmcnt, no RMW). Consumers: wave-0 lanes spin on canaries (1 line/gate),
// bulk-load once, SENT re-poll only as a rare backstop.
__global__ void __launch_bounds__(BLOCK, 1) lstm_pipe(
    const float* __restrict__ X,
    const float* __restrict__ Wih0, const float* __restrict__ Wih,
    const float* __restrict__ Whh,  const float* __restrict__ bih,
    const float* __restrict__ bhh,  const float* __restrict__ Wl,
    const float* __restrict__ bl,   float* __restrict__ out,
    float* __restrict__ hout, int* __restrict__ cny, int hps) {
  __shared__ float vin[3][VINW];        // per-stream [x|h|pad], k-indexed
  __shared__ float part[3][BLOCK];
  __shared__ float bias[ROWS];
  __shared__ float cst[3][UPW];         // c-state, keyed by f%3
  __shared__ float wih0s[ROWS][CDIM];   // l0: raw Wih0 rows (f==0 correction)
  __shared__ float xs[TSTEPS][CDIM];    // l0: f==0 seed = X[t][95][:]
  __shared__ float wlh[CDIM][HP];       // Wl padded (l0 fold + head dot)

  const int tid = threadIdx.x;
  const int bid = blockIdx.x;
  u64* hu = (u64*)hout;

  if (bid >= NL * GPL) {
    // ---------------- head WGs: out[t][f][:] = Wl.h5(f,t)+bl, f%3==hid ----
    const int hid = bid - NL * GPL;
    for (int i = tid; i < CDIM * HP; i += BLOCK) {
      int rr = i / HP, k = i % HP;
      ((float*)wlh)[i] = (k < HND) ? Wl[rr * HND + k] : 0.f;
    }
    for (int i = tid; i < VINW; i += BLOCK) vin[0][i] = 0.f;
    __syncthreads();
    for (int f = hid; f < FSTEPS; f += NHEAD) {
      for (int t = 0; t < TSTEPS; ++t) {
        const int slot = 16 * f + t;
        if (tid < 117) {     // head lags the pipe; data is normally present
          const u64* src = hu + ((size_t)5 * NSLOT + slot) * hps + tid;
          u64 v; long gd = 0;
          for (;;) {
            v = __hip_atomic_load(src, __ATOMIC_RELAXED, AG);
            if (rdy(v)) break;
            if (++gd > (1L << 20)) break;
            if (gd > 2) __builtin_amdgcn_s_sleep(1);
          }
          *(u64*)&vin[0][2 * tid] = v;
        }
        __syncthreads();
        if (tid < 48) {
          int rr = tid >> 2, q = tid & 3;
          const float4* wr = (const float4*)&wlh[rr][0];
          const float4* hv = (const float4*)&vin[0][0];
          float a = 0.f;
          #pragma unroll
          for (int c = 0; c < 15; ++c) {
            float4 x0 = wr[q * 15 + c], y0 = hv[q * 15 + c];
            a = fmaf(x0.w, y0.w, fmaf(x0.z, y0.z, fmaf(x0.y, y0.y, fmaf(x0.x, y0.x, a))));
          }
          a += __shfl_xor(a, 1);
          a += __shfl_xor(a, 2);
          if (q == 0) out[((size_t)t * FSTEPS + f) * CDIM + rr] = a + bl[rr];
        }
        __syncthreads();
      }
    }
    return;
  }

  // ---------------- layer workgroup ----------------
  const int l = bid / GPL, g = bid % GPL;
  const int j0 = g * UPW;
  const int U = min(UPW, HND - j0);            // last WG: 9 units
  const int r = tid & 127, q = tid >> 7;       // matvec row / k-quarter
  const int u = r >> 2, gt = r & 3;
  const int grow = gt * HND + j0 + u;
  const bool rowok = (u < U);

  // ---- small LDS tables
  if (l == 0) {
    for (int i = tid; i < CDIM * HP; i += BLOCK) {
      int rr = i / HP, k = i % HP;
      ((float*)wlh)[i] = (k < HND) ? Wl[rr * HND + k] : 0.f;
    }
    for (int i = tid; i < ROWS * CDIM; i += BLOCK) {
      int rr = i / CDIM, c = i % CDIM;
      int uu = rr >> 2, g2 = rr & 3;
      wih0s[rr][c] = (uu < U) ? Wih0[(g2 * HND + j0 + uu) * CDIM + c] : 0.f;
    }
    for (int i = tid; i < TSTEPS * CDIM; i += BLOCK)
      xs[i / CDIM][i % CDIM] = X[((size_t)(i / CDIM) * 96 + 95) * CDIM + (i % CDIM)];
  }
  for (int i = tid; i < 3 * VINW; i += BLOCK) ((float*)vin)[i] = 0.f;
  __syncthreads();

  // ---- weights into REGISTERS (120-float slice; statically indexed)
  // row layout: [x-weights 240 | Whh 240]; l0 x-weights = Wih0 @ Wl.
  float4 w4[30];
  const float* wihl = Wih + (size_t)(l - 1) * G4H * HND;
  const float* whhl = Whh + (size_t)l * G4H * HND;
  #pragma unroll
  for (int j = 0; j < 30; ++j) {
    float e[4];
    #pragma unroll
    for (int ee = 0; ee < 4; ++ee) {
      const int idx = (q * 30 + j) * 4 + ee;
      float v = 0.f;
      if (rowok) {
        if (idx < HND) {
          if (l == 0) {
            float acc = 0.f;
            #pragma unroll
            for (int c = 0; c < CDIM; ++c) acc = fmaf(wih0s[r][c], wlh[c][idx], acc);
            v = acc;
          } else {
            v = wihl[(size_t)grow * HND + idx];
          }
        } else if (idx >= HP && idx < HP + HND) {
          v = whhl[(size_t)grow * HND + (idx - HP)];
        }
      }
      e[ee] = v;
    }
    w4[j] = make_float4(e[0], e[1], e[2], e[3]);
  }
  if (tid < ROWS) {
    float b = 0.f;
    if (rowok) {
      b = bih[l * G4H + grow] + bhh[l * G4H + grow];
      if (l == 0) {   // fold Wih0 @ bl into the bias
        #pragma unroll
        for (int c = 0; c < CDIM; ++c) b = fmaf(wih0s[tid][c], bl[c], b);
      }
    }
    bias[tid] = b;
  }
  __syncthreads();

  // ---- wavefront tick loop: m = 6f + t
  for (int m = 0; m < NTICK; ++m) {
    const int fh0 = m / 6;
    const int f_hi = (fh0 > 95) ? 95 : fh0;
    const int f_lo = (m < 10) ? 0 : (m - 10) / 6;
    const int nk = f_hi - f_lo + 1;              // active streams (1..3)

    // ---- canary spin: wave-0 lane 8*gate+g polls ONE canary (6 lines max)
    {
      const int* cp = nullptr;
      if (tid < 48) {
        const int gi = tid >> 3, g2 = tid & 7;
        const int k = gi >> 1;
        const bool isx = (gi & 1) == 0;
        const int f = f_lo + k;
        if (f <= f_hi) {
          const int t = m - 6 * f;
          if (isx) {
            if (l == 0) {
              if (f > 0) cp = cny + ((size_t)5 * NSLOT + 16 * (f - 1) + t) * GPL + g2;
            } else {
              cp = cny + ((size_t)(l - 1) * NSLOT + 16 * f + t) * GPL + g2;
            }
          } else if (t > 0) {
            cp = cny + ((size_t)l * NSLOT + 16 * f + t - 1) * GPL + g2;
          }
        }
      }
      if (cp) {
        long gd = 0;
        while (__hip_atomic_load(cp, __ATOMIC_RELAXED, AG) == 0) {
          if (++gd > (1L << 20)) break;          // bail loudly, no hang
          if (gd > 8) __builtin_amdgcn_s_sleep(1);
        }
      }
      __syncthreads();
    }

    // ---- bulk data load, one volley (SENT re-poll = rare backstop)
    const u64 *s0 = nullptr, *s1 = nullptr;
    u64 *d0 = nullptr, *d1 = nullptr;

    auto setup = [&](int w, const u64*& sp, u64*& dp) {
      const int k = w / NWORD;
      const int f = f_lo + k;
      if (f > f_hi) return;
      const int t = m - 6 * f;
      const int o = w - k * NWORD;
      if (o < 117) {                       // x-section word
        if (l == 0 && f == 0) {            // seed from X (12 floats, rest 0)
          vin[k][2 * o]     = (2 * o     < CDIM) ? xs[t][2 * o]     : 0.f;
          vin[k][2 * o + 1] = (2 * o + 1 < CDIM) ? xs[t][2 * o + 1] : 0.f;
          return;
        }
        sp = (l == 0)
           ? hu + ((size_t)5 * NSLOT + 16 * (f - 1) + t) * hps + o
           : hu + ((size_t)(l - 1) * NSLOT + 16 * f + t) * hps + o;
        dp = (u64*)&vin[k][2 * o];
      } else {                             // h-section word
        const int jj = o - 117;
        if (t == 0) {
          vin[k][HP + 2 * jj] = 0.f; vin[k][HP + 2 * jj + 1] = 0.f;
          return;
        }
        sp = hu + ((size_t)l * NSLOT + 16 * f + t - 1) * hps + jj;
        dp = (u64*)&vin[k][HP + 2 * jj];
      }
    };
    setup(tid, s0, d0);
    if (tid + BLOCK < 3 * NWORD) setup(tid + BLOCK, s1, d1);

    long gd = 0;
    while (s0 || s1) {
      if (s0) { u64 v = __hip_atomic_load(s0, __ATOMIC_RELAXED, AG); if (rdy(v)) { *d0 = v; s0 = nullptr; } }
      if (s1) { u64 v = __hip_atomic_load(s1, __ATOMIC_RELAXED, AG); if (rdy(v)) { *d1 = v; s1 = nullptr; } }
      if (++gd > (1L << 20)) break;
      if (gd > 4) __builtin_amdgcn_s_sleep(1);
    }
    __syncthreads();

    // ---- matvec: active streams only; weights in regs, vin broadcast reads
    const float4* va = (const float4*)&vin[0][0];
    const float4* vb = (const float4*)&vin[1][0];
    const float4* vc = (const float4*)&vin[2][0];
    float a0 = 0.f, a1 = 0.f, a2 = 0.f;
    #pragma unroll
    for (int j = 0; j < 30; ++j) {
      const int c = q * 30 + j;
      const float4 wv = w4[j];
      const float4 y0 = va[c];
      a0 = fmaf(wv.x, y0.x, fmaf(wv.y, y0.y, fmaf(wv.z, y0.z, fmaf(wv.w, y0.w, a0))));
    }
    if (nk > 1) {
      #pragma unroll
      for (int j = 0; j < 30; ++j) {
        const int c = q * 30 + j;
        const float4 wv = w4[j];
        const float4 y1 = vb[c];
        a1 = fmaf(wv.x, y1.x, fmaf(wv.y, y1.y, fmaf(wv.z, y1.z, fmaf(wv.w, y1.w, a1))));
      }
    }
    if (nk > 2) {
      #pragma unroll
      for (int j = 0; j < 30; ++j) {
        const int c = q * 30 + j;
        const float4 wv = w4[j];
        const float4 y2 = vc[c];
        a2 = fmaf(wv.x, y2.x, fmaf(wv.y, y2.y, fmaf(wv.z, y2.z, fmaf(wv.w, y2.w, a2))));
      }
    }
    part[0][tid] = a0; part[1][tid] = a1; part[2][tid] = a2;
    __syncthreads();

    // ---- cell + publish + canary (threads 0..95: stream k = tid/32)
    if (tid < 96) {
      const int k = tid >> 5, uu = tid & 31;
      const int f = f_lo + k;
      const bool act = (f <= f_hi);
      float hn = 0.f;
      int t = 0;
      if (act) {
        t = m - 6 * f;
        const int b3 = f % 3;
        float gg[4];
        #pragma unroll
        for (int g2 = 0; g2 < 4; ++g2) {
          const int rr = 4 * uu + g2;
          float s = part[k][rr] + part[k][rr + 128] + part[k][rr + 256] +
                    part[k][rr + 384] + bias[rr];
          if (l == 0 && f == 0) {          // f==0: x is the raw 12-dim seed
            #pragma unroll
            for (int c = 0; c < CDIM; ++c) s = fmaf(wih0s[rr][c], xs[t][c], s);
          }
          gg[g2] = s;
        }
        if (uu < U) {
          const float cp2 = (t == 0) ? 0.f : cst[b3][uu];
          const float cn = sigf(gg[1]) * cp2 + sigf(gg[0]) * tanhf(gg[2]);
          hn = sigf(gg[3]) * tanhf(cn);
          cst[b3][uu] = cn;
        }
      }
      const float hi = __shfl(hn, (tid & 63) | 1);   // pair-pack (hn=0 beyond U)
      if (act && (uu & 1) == 0 && uu < U) {
        const u64 pv = ((u64)__float_as_uint(hi) << 32) | (u64)__float_as_uint(hn);
        __hip_atomic_store(hu + ((size_t)l * NSLOT + 16 * f + t) * hps + (j0 >> 1) + (uu >> 1),
                           pv, __ATOMIC_RELAXED, AG);
      }
      // per-producer canary AFTER this thread's data stores (no vmcnt, no RMW;
      // consumer's SENT backstop covers any store reordering)
      if (act && uu == 0)   // slot = 16f + (m-6f) = 10f + m
        __hip_atomic_store(cny + ((size_t)l * NSLOT + 10 * f + m) * GPL + g, 1,
                           __ATOMIC_RELAXED, AG);
    }
    // 3 barriers/tick; publish completes before next tick's stage barrier.
  }
}

extern "C" void kernel_launch(void* const* d_in, const int* in_sizes, int n_in,
                              void* d_out, int out_size, void* d_ws, size_t ws_size,
                              hipStream_t stream) {
  const float* X    = (const float*)d_in[0];
  const float* Wih0 = (const float*)d_in[1];
  const float* Wih  = (const float*)d_in[2];
  const float* Whh  = (const float*)d_in[3];
  const float* bih  = (const float*)d_in[4];
  const float* bhh  = (const float*)d_in[5];
  const float* Wl   = (const float*)d_in[6];
  const float* bl   = (const float*)d_in[7];

  // workspace: hout[6][1536][hp] f32 + cny[6][1536][GPL] i32
  const size_t cnyN = (size_t)NL * NSLOT * GPL;
  size_t need240 = (size_t)NL * NSLOT * 240 * 4 + cnyN * 4;
  const int hp = (ws_size >= need240) ? 240 : 234;
  float* hout = (float*)d_ws;
  int* cny = (int*)(hout + (size_t)NL * NSLOT * hp);

  init_kernel<<<2048, 256, 0, stream>>>((unsigned*)hout, cny, hp);
  lstm_pipe<<<NL * GPL + NHEAD, BLOCK, 0, stream>>>(
      X, Wih0, Wih, Whh, bih, bhh, Wl, bl, (float*)d_out, hout, cny, hp / 2);
}

// Round 10
// 2996.719 us; speedup vs baseline: 1.6015x; 1.6015x over previous
//
#include <hip/hip_runtime.h>

// ---------------- problem constants ----------------
#define HND    233
#define NL     6
#define GPL    8              // WGs per layer
#define UPW    32             // units per WG (8*32 = 256 >= 233)
#define ROWS   128            // gate rows per WG
#define TSTEPS 16
#define FSTEPS 96
#define NSLOT  (TSTEPS*FSTEPS)
#define CDIM   12
#define G4H    (4*HND)        // 932
#define HP     240            // hout row stride target (floats)
#define VINW   496            // vin buffer: [x 240 | h 240 | pad 16]
#define ACO    11             // dilated schedule: T = 11 f + 2 t (+2l wall lag)
#define NSTEP  (ACO*95 + 2*15 + 1)   // 1076 local steps
#define NHEAD  3
#define BLOCK  512
#define NWORD  234            // u64 words per stream (117 x + 117 h)
#define AG     __HIP_MEMORY_SCOPE_AGENT
#define SENT   0x7FBADBADu    // NaN pattern: unreachable by real data
#define PLIM   (1L << 15)     // poll bail (loud NaN, no long hang)

typedef unsigned long long u64;

__device__ __forceinline__ float sigf(float x) { return 1.f / (1.f + expf(-x)); }
__device__ __forceinline__ bool rdy(u64 v) {
  return ((unsigned)v != SENT) && ((unsigned)(v >> 32) != SENT);
}

// Active (f,t) streams at local step n: t = (n - 11 f)/2, parity-matched.
// Window width 31 and a=11 odd guarantee ns <= 2 (f and f-2 only).
__device__ __forceinline__ int build(int n, int* fl, int* tl) {
  int ns = 0;
  const int fm = n / ACO;
  #pragma unroll
  for (int df = 2; df >= 0; --df) {
    const int f = fm - df;
    const int r = n - ACO * f;
    if (f >= 0 && f <= 95 && r >= 0 && r <= 30 && !(r & 1)) {
      fl[ns] = f; tl[ns] = r >> 1; ++ns;
    }
  }
  return ns;
}

// u64-word address for word o of stream (f,t) at layer l; null => local zero/seed.
__device__ __forceinline__ const u64* word_addr(int l, int f, int t, int o,
                                                const u64* hu, int hps) {
  if (o < 117) {                                   // x-section
    if (l == 0) {
      if (f == 0) return nullptr;                  // seed handled in cell
      return hu + ((size_t)5 * NSLOT + 16 * (f - 1) + t) * hps + o;
    }
    return hu + ((size_t)(l - 1) * NSLOT + 16 * f + t) * hps + o;
  }
  if (t == 0) return nullptr;                      // h(t=0) = 0
  return hu + ((size_t)l * NSLOT + 16 * f + (t - 1)) * hps + (o - 117);
}

// Re-poison hout: data dwords -> SENT, pad dwords -> 0.
__global__ void init_kernel(unsigned* __restrict__ hout, int hp) {
  size_t i = (size_t)blockIdx.x * blockDim.x + threadIdx.x;
  size_t stride = (size_t)gridDim.x * blockDim.x;
  const size_t nh = (size_t)NL * NSLOT * hp;
  for (size_t k = i; k < nh; k += stride) hout[k] = ((int)(k % hp) < HND) ? SENT : 0u;
}

// grid: NL*GPL layer WGs + NHEAD head WGs, 512 threads.
// Protocol: MALL relaxed atomics only; consumers poll the DATA (SENT = not
// ready); steady state uses a 1-step-early register prefetch that hits because
// every dataflow edge spans >=2 local steps in the dilated schedule.
__global__ void __launch_bounds__(BLOCK, 1) lstm_pipe(
    const float* __restrict__ X,
    const float* __restrict__ Wih0, const float* __restrict__ Wih,
    const float* __restrict__ Whh,  const float* __restrict__ bih,
    const float* __restrict__ bhh,  const float* __restrict__ Wl,
    const float* __restrict__ bl,   float* __restrict__ out,
    float* __restrict__ hout, int hps) {
  __shared__ float vin[3][VINW];        // stream buffers, keyed f%3
  __shared__ float part[2][BLOCK];      // matvec partials, keyed list position
  __shared__ float bias[ROWS];
  __shared__ float foldb[ROWS];         // l0: Wih0 @ bl (f>=1 only)
  __shared__ float cst[3][UPW];         // c-state, keyed f%3
  __shared__ float wih0s[ROWS][CDIM];   // l0: raw Wih0 rows (f==0 correction)
  __shared__ float xs[TSTEPS][CDIM];    // l0: f==0 seed = X[t][95][:]
  __shared__ float wlh[CDIM][HP];       // Wl padded (l0 fold + head dot)

  const int tid = threadIdx.x;
  const int bid = blockIdx.x;
  u64* hu = (u64*)hout;

  if (bid >= NL * GPL) {
    // ---------------- head WGs: out[t][f][:] = Wl.h5(f,t)+bl, f%3==hid ----
    const int hid = bid - NL * GPL;
    for (int i = tid; i < CDIM * HP; i += BLOCK) {
      int rr = i / HP, k = i % HP;
      ((float*)wlh)[i] = (k < HND) ? Wl[rr * HND + k] : 0.f;
    }
    for (int i = tid; i < VINW; i += BLOCK) vin[0][i] = 0.f;
    __syncthreads();
    for (int f = hid; f < FSTEPS; f += NHEAD) {
      for (int t = 0; t < TSTEPS; ++t) {
        if (tid < 117) {
          const u64* src = hu + ((size_t)5 * NSLOT + 16 * f + t) * hps + tid;
          u64 v; long gd = 0;
          for (;;) {
            v = __hip_atomic_load(src, __ATOMIC_RELAXED, AG);
            if (rdy(v)) break;
            if (++gd > PLIM) break;
            if (gd > 2) __builtin_amdgcn_s_sleep(2);
          }
          *(u64*)&vin[0][2 * tid] = v;
        }
        __syncthreads();
        if (tid < 48) {
          int rr = tid >> 2, q = tid & 3;
          const float4* wr = (const float4*)&wlh[rr][0];
          const float4* hv = (const float4*)&vin[0][0];
          float a = 0.f;
          #pragma unroll
          for (int c = 0; c < 15; ++c) {
            float4 x0 = wr[q * 15 + c], y0 = hv[q * 15 + c];
            a = fmaf(x0.w, y0.w, fmaf(x0.z, y0.z, fmaf(x0.y, y0.y, fmaf(x0.x, y0.x, a))));
          }
          a += __shfl_xor(a, 1);
          a += __shfl_xor(a, 2);
          if (q == 0) out[((size_t)t * FSTEPS + f) * CDIM + rr] = a + bl[rr];
        }
        __syncthreads();
      }
    }
    return;
  }

  // ---------------- layer workgroup ----------------
  const int l = bid / GPL, g = bid % GPL;
  const int j0 = g * UPW;
  const int U = min(UPW, HND - j0);            // last WG: 9 units
  const int r = tid & 127, q = tid >> 7;       // matvec row / k-quarter
  const int u = r >> 2, gt = r & 3;
  const int grow = gt * HND + j0 + u;
  const bool rowok = (u < U);

  // ---- small LDS tables
  if (l == 0) {
    for (int i = tid; i < CDIM * HP; i += BLOCK) {
      int rr = i / HP, k = i % HP;
      ((float*)wlh)[i] = (k < HND) ? Wl[rr * HND + k] : 0.f;
    }
    for (int i = tid; i < ROWS * CDIM; i += BLOCK) {
      int rr = i / CDIM, c = i % CDIM;
      int uu = rr >> 2, g2 = rr & 3;
      wih0s[rr][c] = (uu < U) ? Wih0[(g2 * HND + j0 + uu) * CDIM + c] : 0.f;
    }
    for (int i = tid; i < TSTEPS * CDIM; i += BLOCK)
      xs[i / CDIM][i % CDIM] = X[((size_t)(i / CDIM) * 96 + 95) * CDIM + (i % CDIM)];
  }
  for (int i = tid; i < 3 * VINW; i += BLOCK) ((float*)vin)[i] = 0.f;
  __syncthreads();

  // ---- weights into REGISTERS (120-float slice; statically indexed)
  // row layout: [x-weights 240 | Whh 240]; l0 x-weights = Wih0 @ Wl.
  float4 w4[30];
  const float* wihl = Wih + (size_t)(l - 1) * G4H * HND;
  const float* whhl = Whh + (size_t)l * G4H * HND;
  #pragma unroll
  for (int j = 0; j < 30; ++j) {
    float e[4];
    #pragma unroll
    for (int ee = 0; ee < 4; ++ee) {
      const int idx = (q * 30 + j) * 4 + ee;
      float v = 0.f;
      if (rowok) {
        if (idx < HND) {
          if (l == 0) {
            float acc = 0.f;
            #pragma unroll
            for (int c = 0; c < CDIM; ++c) acc = fmaf(wih0s[r][c], wlh[c][idx], acc);
            v = acc;
          } else {
            v = wihl[(size_t)grow * HND + idx];
          }
        } else if (idx >= HP && idx < HP + HND) {
          v = whhl[(size_t)grow * HND + (idx - HP)];
        }
      }
      e[ee] = v;
    }
    w4[j] = make_float4(e[0], e[1], e[2], e[3]);
  }
  if (tid < ROWS) {
    float b = 0.f, fb = 0.f;
    if (rowok) {
      b = bih[l * G4H + grow] + bhh[l * G4H + grow];
      if (l == 0) {   // Wih0 @ bl: valid only for the folded-token path (f>=1)
        #pragma unroll
        for (int c = 0; c < CDIM; ++c) fb = fmaf(wih0s[tid][c], bl[c], fb);
      }
    }
    bias[tid] = b;
    foldb[tid] = fb;
  }
  __syncthreads();

  // ---- per-thread exchange-word assignment (fixed for the whole loop)
  const int jme = tid >> 8;            // stream list position 0/1
  const int ome = tid & 255;           // word index within stream
  const bool wok = ome < NWORD;

  u64 pfv = 0;                         // prefetched word (issued last step)
  int pff = -1;                        // f it belongs to (-1 = none)
  int fl[2], tl[2];

  for (int n = 0; n < NSTEP; ++n) {
    const int ns = build(n, fl, tl);

    // ---- STAGE: consume prefetch (compiler waits the load exactly here),
    //      fallback-poll if missing, write vin LDS.
    if (jme < ns && wok) {
      const int f = fl[jme], t = tl[jme], sg = f % 3;
      float* dst = (ome < 117) ? &vin[sg][2 * ome] : &vin[sg][HP + 2 * (ome - 117)];
      const u64* ap = word_addr(l, f, t, ome, hu, hps);
      if (ap) {
        u64 v = (pff == f) ? pfv : __hip_atomic_load(ap, __ATOMIC_RELAXED, AG);
        long gd = 0;
        while (!rdy(v)) {                       // rare: drift > 1 step
          v = __hip_atomic_load(ap, __ATOMIC_RELAXED, AG);
          if (++gd > PLIM) break;               // bail loudly (NaN), no hang
          if (gd > 16) __builtin_amdgcn_s_sleep(2);
        }
        *(u64*)dst = v;
      } else if (ome >= 117) {                  // t==0: h-section zeros
        dst[0] = 0.f; dst[1] = 0.f;
      }
      // l0 && f==0 x-words: slot pristine zeros (seed enters via cell).
    }

    // ---- PREFETCH for step n+1 (inputs were produced at <= n-1: present)
    pff = -1;
    {
      int fl2[2], tl2[2];
      const int ns2 = build(n + 1, fl2, tl2);
      if (jme < ns2 && wok) {
        const u64* ap = word_addr(l, fl2[jme], tl2[jme], ome, hu, hps);
        if (ap) {
          pfv = __hip_atomic_load(ap, __ATOMIC_RELAXED, AG);
          pff = fl2[jme];
        }
      }
    }

    // raw barrier: LDS drained, prefetch loads stay in flight (counted waits)
    asm volatile("s_waitcnt lgkmcnt(0)" ::: "memory");
    __builtin_amdgcn_s_barrier();

    // ---- MATVEC: <=2 streams, weights in regs, vin via wave-broadcast reads
    if (ns > 0) {
      const float4* va = (const float4*)&vin[fl[0] % 3][0];
      float a0 = 0.f;
      #pragma unroll
      for (int j = 0; j < 30; ++j) {
        const float4 wv = w4[j];
        const float4 y0 = va[q * 30 + j];
        a0 = fmaf(wv.x, y0.x, fmaf(wv.y, y0.y, fmaf(wv.z, y0.z, fmaf(wv.w, y0.w, a0))));
      }
      part[0][tid] = a0;
      if (ns > 1) {
        const float4* vb = (const float4*)&vin[fl[1] % 3][0];
        float a1 = 0.f;
        #pragma unroll
        for (int j = 0; j < 30; ++j) {
          const float4 wv = w4[j];
          const float4 y1 = vb[q * 30 + j];
          a1 = fmaf(wv.x, y1.x, fmaf(wv.y, y1.y, fmaf(wv.z, y1.z, fmaf(wv.w, y1.w, a1))));
        }
        part[1][tid] = a1;
      }
    }
    asm volatile("s_waitcnt lgkmcnt(0)" ::: "memory");
    __builtin_amdgcn_s_barrier();

    // ---- CELL + publish (wave 0: stream k = tid/32)
    if (tid < 64) {
      const int k = tid >> 5, uu = tid & 31;
      float hn = 0.f;
      int f = 0, t = 0;
      const bool act = (k < ns);
      if (act) {
        f = fl[k]; t = tl[k];
        const int b3 = f % 3;
        float gg[4];
        #pragma unroll
        for (int g2 = 0; g2 < 4; ++g2) {
          const int rr = 4 * uu + g2;
          float s = part[k][rr] + part[k][rr + 128] + part[k][rr + 256] +
                    part[k][rr + 384] + bias[rr];
          if (l == 0) {
            if (f == 0) {                    // x = raw 12-dim seed
              #pragma unroll
              for (int c = 0; c < CDIM; ++c) s = fmaf(wih0s[rr][c], xs[t][c], s);
            } else {
              s += foldb[rr];                // folded Wih0 @ bl
            }
          }
          gg[g2] = s;
        }
        if (uu < U) {
          const float cp = (t == 0) ? 0.f : cst[b3][uu];
          const float cn = sigf(gg[1]) * cp + sigf(gg[0]) * tanhf(gg[2]);
          hn = sigf(gg[3]) * tanhf(cn);
          cst[b3][uu] = cn;
        }
      }
      const float hi = __shfl(hn, tid | 1);  // pair-pack (hn=0 beyond U)
      if (act && (uu & 1) == 0 && uu < U) {
        const u64 pv = ((u64)__float_as_uint(hi) << 32) | (u64)__float_as_uint(hn);
        __hip_atomic_store(hu + ((size_t)l * NSLOT + 16 * f + t) * hps +
                               (j0 >> 1) + (uu >> 1),
                           pv, __ATOMIC_RELAXED, AG);
      }
    }
    // no trailing barrier: next stage writes a different vin slot (f%3 keying,
    // adjacent steps never collide); part reuse is fenced by barrier-1.
  }
}

extern "C" void kernel_launch(void* const* d_in, const int* in_sizes, int n_in,
                              void* d_out, int out_size, void* d_ws, size_t ws_size,
                              hipStream_t stream) {
  const float* X    = (const float*)d_in[0];
  const float* Wih0 = (const float*)d_in[1];
  const float* Wih  = (const float*)d_in[2];
  const float* Whh  = (const float*)d_in[3];
  const float* bih  = (const float*)d_in[4];
  const float* bhh  = (const float*)d_in[5];
  const float* Wl   = (const float*)d_in[6];
  const float* bl   = (const float*)d_in[7];

  // workspace: hout[6][1536][hp] f32 (~8.85 MB at hp=240)
  const size_t HN = (size_t)NL * NSLOT;
  const int hp = (ws_size >= HN * 240 * 4) ? 240 : 234;
  float* hout = (float*)d_ws;

  init_kernel<<<2048, 256, 0, stream>>>((unsigned*)hout, hp);
  lstm_pipe<<<NL * GPL + NHEAD, BLOCK, 0, stream>>>(
      X, Wih0, Wih, Whh, bih, bhh, Wl, bl, (float*)d_out, hout, hp / 2);
}

// Round 11
// 2761.704 us; speedup vs baseline: 1.7377x; 1.0851x over previous
//
#include <hip/hip_runtime.h>

// ---------------- problem constants ----------------
#define HND    233
#define NL     6
#define GPL    8              // WGs per layer
#define UPW    32             // units per WG (8*32 = 256 >= 233)
#define ROWS   128            // gate rows per WG
#define TSTEPS 16
#define FSTEPS 96
#define NSLOT  (TSTEPS*FSTEPS)
#define CDIM   12
#define G4H    (4*HND)        // 932
#define HP     240            // hout row stride target (floats)
#define VINW   496            // vin buffer: [x 240 | h 240 | pad 16]
#define NTICK  (6*95+15+1)    // 586 wavefront ticks (critical-path optimal)
#define NHEAD  3
#define BLOCK  512
#define NWORD  234            // u64 words per stream (117 x + 117 h)
#define AG     __HIP_MEMORY_SCOPE_AGENT
#define SENT   0x7FBADBADu    // NaN pattern: unreachable by real data
#define PLIM   (1L << 18)     // poll bail (loud NaN, no hang)

typedef unsigned long long u64;

__device__ __forceinline__ float sigf(float x) { return 1.f / (1.f + expf(-x)); }
__device__ __forceinline__ bool rdy(u64 v) {
  return ((unsigned)v != SENT) && ((unsigned)(v >> 32) != SENT);
}

// Active (f,t) streams at tick m: t = m - 6f in [0,15]; ns <= 3.
__device__ __forceinline__ int build(int m, int* fl, int* tl) {
  const int fh0 = m / 6;
  const int f_hi = (fh0 > 95) ? 95 : fh0;
  const int f_lo = (m < 10) ? 0 : (m - 10) / 6;
  const int ns = f_hi - f_lo + 1;
  #pragma unroll
  for (int k = 0; k < 3; ++k) { fl[k] = f_lo + k; tl[k] = m - 6 * (f_lo + k); }
  return ns;
}

// Re-poison hout: data dwords -> SENT, pad dwords -> 0.
__global__ void init_kernel(unsigned* __restrict__ hout, int hp) {
  size_t i = (size_t)blockIdx.x * blockDim.x + threadIdx.x;
  size_t stride = (size_t)gridDim.x * blockDim.x;
  const size_t nh = (size_t)NL * NSLOT * hp;
  for (size_t k = i; k < nh; k += stride) hout[k] = ((int)(k % hp) < HND) ? SENT : 0u;
}

// grid: NL*GPL layer WGs + NHEAD head WGs, 512 threads (8 waves).
// Round-6 protocol: MALL relaxed atomics only; consumers poll the DATA itself.
// Per tick: [stage volley -> barrier -> matvec (in-wave shfl reduce) ->
// barrier -> cell (+own-slice LDS write) + publish].
__global__ void __launch_bounds__(BLOCK, 1) lstm_pipe(
    const float* __restrict__ X,
    const float* __restrict__ Wih0, const float* __restrict__ Wih,
    const float* __restrict__ Whh,  const float* __restrict__ bih,
    const float* __restrict__ bhh,  const float* __restrict__ Wl,
    const float* __restrict__ bl,   float* __restrict__ out,
    float* __restrict__ hout, int hps) {
  __shared__ float vin[3][VINW];        // stream buffers, keyed f%3
  __shared__ float bias[ROWS];
  __shared__ float foldb[ROWS];         // l0: Wih0 @ bl (f>=1 only)
  __shared__ float cst[3][UPW];         // c-state, keyed f%3
  __shared__ float wih0s[ROWS][CDIM];   // l0: raw Wih0 rows (f==0 correction)
  __shared__ float xs[TSTEPS][CDIM];    // l0: f==0 seed = X[t][95][:]
  __shared__ float wlh[CDIM][HP];       // Wl padded (l0 fold + head dot)

  const int tid = threadIdx.x;
  const int bid = blockIdx.x;
  u64* hu = (u64*)hout;

  if (bid >= NL * GPL) {
    // ---------------- head WGs: out[t][f][:] = Wl.h5(f,t)+bl, f%3==hid ----
    const int hid = bid - NL * GPL;
    for (int i = tid; i < CDIM * HP; i += BLOCK) {
      int rr = i / HP, k = i % HP;
      ((float*)wlh)[i] = (k < HND) ? Wl[rr * HND + k] : 0.f;
    }
    for (int i = tid; i < VINW; i += BLOCK) vin[0][i] = 0.f;
    __syncthreads();
    for (int f = hid; f < FSTEPS; f += NHEAD) {
      for (int t = 0; t < TSTEPS; ++t) {
        if (tid < 117) {
          const u64* src = hu + ((size_t)5 * NSLOT + 16 * f + t) * hps + tid;
          u64 v; long gd = 0;
          for (;;) {
            v = __hip_atomic_load(src, __ATOMIC_RELAXED, AG);
            if (rdy(v)) break;
            if (++gd > PLIM) break;
            if (gd > 4) __builtin_amdgcn_s_sleep(1);
          }
          *(u64*)&vin[0][2 * tid] = v;
        }
        __syncthreads();
        if (tid < 48) {
          int rr = tid >> 2, q = tid & 3;
          const float4* wr = (const float4*)&wlh[rr][0];
          const float4* hv = (const float4*)&vin[0][0];
          float a = 0.f;
          #pragma unroll
          for (int c = 0; c < 15; ++c) {
            float4 x0 = wr[q * 15 + c], y0 = hv[q * 15 + c];
            a = fmaf(x0.w, y0.w, fmaf(x0.z, y0.z, fmaf(x0.y, y0.y, fmaf(x0.x, y0.x, a))));
          }
          a += __shfl_xor(a, 1);
          a += __shfl_xor(a, 2);
          if (q == 0) out[((size_t)t * FSTEPS + f) * CDIM + rr] = a + bl[rr];
        }
        __syncthreads();
      }
    }
    return;
  }

  // ---------------- layer workgroup ----------------
  const int l = bid / GPL, g = bid % GPL;
  const int j0 = g * UPW;
  const int U = min(UPW, HND - j0);            // last WG: 9 units
  const int wave = tid >> 6, ln = tid & 63;
  const int rr = ln & 15, q = ln >> 4;         // in-wave: 16 rows x 4 quarters
  const int row = wave * 16 + rr;              // 0..127
  const int u = row >> 2, gt = row & 3;
  const int grow = gt * HND + j0 + u;
  const bool rowok = (u < U);

  // ---- small LDS tables
  if (l == 0) {
    for (int i = tid; i < CDIM * HP; i += BLOCK) {
      int r2 = i / HP, k = i % HP;
      ((float*)wlh)[i] = (k < HND) ? Wl[r2 * HND + k] : 0.f;
    }
    for (int i = tid; i < ROWS * CDIM; i += BLOCK) {
      int r2 = i / CDIM, c = i % CDIM;
      int uu = r2 >> 2, g2 = r2 & 3;
      wih0s[r2][c] = (uu < U) ? Wih0[(g2 * HND + j0 + uu) * CDIM + c] : 0.f;
    }
    for (int i = tid; i < TSTEPS * CDIM; i += BLOCK)
      xs[i / CDIM][i % CDIM] = X[((size_t)(i / CDIM) * 96 + 95) * CDIM + (i % CDIM)];
  }
  for (int i = tid; i < 3 * VINW; i += BLOCK) ((float*)vin)[i] = 0.f;
  __syncthreads();

  // ---- weights into REGISTERS (120-float slice; statically indexed)
  // row layout: [x-weights 240 | Whh 240]; l0 x-weights = Wih0 @ Wl.
  float4 w4[30];
  const float* wihl = Wih + (size_t)(l - 1) * G4H * HND;
  const float* whhl = Whh + (size_t)l * G4H * HND;
  #pragma unroll
  for (int j = 0; j < 30; ++j) {
    float e[4];
    #pragma unroll
    for (int ee = 0; ee < 4; ++ee) {
      const int idx = (q * 30 + j) * 4 + ee;
      float v = 0.f;
      if (rowok) {
        if (idx < HND) {
          if (l == 0) {
            float acc = 0.f;
            #pragma unroll
            for (int c = 0; c < CDIM; ++c) acc = fmaf(wih0s[row][c], wlh[c][idx], acc);
            v = acc;
          } else {
            v = wihl[(size_t)grow * HND + idx];
          }
        } else if (idx >= HP && idx < HP + HND) {
          v = whhl[(size_t)grow * HND + (idx - HP)];
        }
      }
      e[ee] = v;
    }
    w4[j] = make_float4(e[0], e[1], e[2], e[3]);
  }
  if (tid < ROWS) {
    float b = 0.f, fb = 0.f;
    if ((tid >> 2) < U) {
      const int gr2 = (tid & 3) * HND + j0 + (tid >> 2);
      b = bih[l * G4H + gr2] + bhh[l * G4H + gr2];
      if (l == 0) {   // Wih0 @ bl: folded-token path only (f>=1)
        #pragma unroll
        for (int c = 0; c < CDIM; ++c) fb = fmaf(wih0s[tid][c], bl[c], fb);
      }
    }
    bias[tid] = b;
    foldb[tid] = fb;
  }
  __syncthreads();

  int fl[3], tl[3];

  for (int m = 0; m < NTICK; ++m) {
    const int ns = build(m, fl, tl);

    // ---- STAGE: poll the data itself (words w = tid, tid+512 of 3*234)
    const u64 *s0 = nullptr, *s1 = nullptr;
    u64 *d0 = nullptr, *d1 = nullptr;

    auto setup = [&](int w, const u64*& sp, u64*& dp) {
      const int k = w / NWORD;
      if (k >= ns) return;
      const int f = fl[k], t = tl[k], sg = f % 3;
      const int o = w - k * NWORD;
      if (o < 117) {                       // x-section word
        if (l == 0 && f == 0) return;      // pristine zeros (seed via cell)
        sp = (l == 0)
           ? hu + ((size_t)5 * NSLOT + 16 * (f - 1) + t) * hps + o
           : hu + ((size_t)(l - 1) * NSLOT + 16 * f + t) * hps + o;
        dp = (u64*)&vin[sg][2 * o];
      } else {                             // h-section word
        const int jj = o - 117;
        float* dst = &vin[sg][HP + 2 * jj];
        if (t == 0) { dst[0] = 0.f; dst[1] = 0.f; return; }
        if ((jj >> 4) == g) return;        // own slice: cell wrote it last tick
        sp = hu + ((size_t)l * NSLOT + 16 * f + (t - 1)) * hps + jj;
        dp = (u64*)dst;
      }
    };
    setup(tid, s0, d0);
    if (tid + BLOCK < 3 * NWORD) setup(tid + BLOCK, s1, d1);

    long gd = 0;
    while (s0 || s1) {
      if (s0) { u64 v = __hip_atomic_load(s0, __ATOMIC_RELAXED, AG);
                if (rdy(v)) { *d0 = v; s0 = nullptr; } }
      if (s1) { u64 v = __hip_atomic_load(s1, __ATOMIC_RELAXED, AG);
                if (rdy(v)) { *d1 = v; s1 = nullptr; } }
      if (++gd > PLIM) break;              // bail loudly (NaN), no hang
      if (gd > 6) __builtin_amdgcn_s_sleep(1);
    }
    __syncthreads();

    // ---- MATVEC: weights in regs; vin broadcast reads; in-wave reduce
    float r0 = 0.f, r1 = 0.f, r2 = 0.f;
    {
      const float4* va = (const float4*)&vin[fl[0] % 3][0];
      float a = 0.f;
      #pragma unroll
      for (int j = 0; j < 30; ++j) {
        const float4 wv = w4[j];
        const float4 y = va[q * 30 + j];
        a = fmaf(wv.x, y.x, fmaf(wv.y, y.y, fmaf(wv.z, y.z, fmaf(wv.w, y.w, a))));
      }
      a += __shfl_xor(a, 16);
      a += __shfl_xor(a, 32);
      r0 = a + bias[row];
    }
    if (ns > 1) {
      const float4* vb = (const float4*)&vin[fl[1] % 3][0];
      float a = 0.f;
      #pragma unroll
      for (int j = 0; j < 30; ++j) {
        const float4 wv = w4[j];
        const float4 y = vb[q * 30 + j];
        a = fmaf(wv.x, y.x, fmaf(wv.y, y.y, fmaf(wv.z, y.z, fmaf(wv.w, y.w, a))));
      }
      a += __shfl_xor(a, 16);
      a += __shfl_xor(a, 32);
      r1 = a + bias[row];
    }
    if (ns > 2) {
      const float4* vc = (const float4*)&vin[fl[2] % 3][0];
      float a = 0.f;
      #pragma unroll
      for (int j = 0; j < 30; ++j) {
        const float4 wv = w4[j];
        const float4 y = vc[q * 30 + j];
        a = fmaf(wv.x, y.x, fmaf(wv.y, y.y, fmaf(wv.z, y.z, fmaf(wv.w, y.w, a))));
      }
      a += __shfl_xor(a, 16);
      a += __shfl_xor(a, 32);
      r2 = a + bias[row];
    }
    __syncthreads();   // all vin reads done before cell/next-stage writes

    // ---- CELL + own-slice LDS write + publish (per wave, lanes 0..3)
    const int v4 = ln & 3;                 // unit-in-wave (valid for ln<4)
    const int uu = 4 * wave + v4;          // unit-in-WG 0..31
    const int rowc = 4 * uu;               // its 4 gate rows
    #pragma unroll
    for (int k = 0; k < 3; ++k) {
      if (k >= ns) break;
      const int f = fl[k], t = tl[k], b3 = f % 3;
      const float gv = (k == 0) ? r0 : (k == 1) ? r1 : r2;
      float hn = 0.f;
      // gather this unit's 4 gates from lanes 4*v4+g2 (q=0 copies)
      float gg[4];
      #pragma unroll
      for (int g2 = 0; g2 < 4; ++g2) gg[g2] = __shfl(gv, 4 * v4 + g2);
      if (ln < 4 && uu < U) {
        #pragma unroll
        for (int g2 = 0; g2 < 4; ++g2) {
          if (l == 0) {
            if (f == 0) {                  // x = raw 12-dim seed
              float s = gg[g2];
              #pragma unroll
              for (int c = 0; c < CDIM; ++c) s = fmaf(wih0s[rowc + g2][c], xs[t][c], s);
              gg[g2] = s;
            } else {
              gg[g2] += foldb[rowc + g2];  // folded Wih0 @ bl
            }
          }
        }
        const float cp = (t == 0) ? 0.f : cst[b3][uu];
        const float cn = sigf(gg[1]) * cp + sigf(gg[0]) * tanhf(gg[2]);
        hn = sigf(gg[3]) * tanhf(cn);
        cst[b3][uu] = cn;
        vin[b3][HP + j0 + uu] = hn;        // own slice for next tick (skip-poll)
      }
      // pair-pack + publish: lanes 0,1 per wave store one u64 each
      const float lo = __shfl(hn, 2 * (ln & 1));
      const float hi = __shfl(hn, 2 * (ln & 1) + 1);
      if (ln < 2) {
        const int pairu = 4 * wave + 2 * ln;
        if (pairu < U) {
          const u64 pv = ((u64)__float_as_uint(hi) << 32) | (u64)__float_as_uint(lo);
          __hip_atomic_store(hu + ((size_t)l * NSLOT + 16 * f + t) * hps +
                                 (j0 >> 1) + (pairu >> 1),
                             pv, __ATOMIC_RELAXED, AG);
        }
      }
    }
    // no barrier after cell: next stage never touches own-slice words, and
    // matvec(m+1) reads come after the next stage barrier.
  }
}

extern "C" void kernel_launch(void* const* d_in, const int* in_sizes, int n_in,
                              void* d_out, int out_size, void* d_ws, size_t ws_size,
                              hipStream_t stream) {
  const float* X    = (const float*)d_in[0];
  const float* Wih0 = (const float*)d_in[1];
  const float* Wih  = (const float*)d_in[2];
  const float* Whh  = (const float*)d_in[3];
  const float* bih  = (const float*)d_in[4];
  const float* bhh  = (const float*)d_in[5];
  const float* Wl   = (const float*)d_in[6];
  const float* bl   = (const float*)d_in[7];

  // workspace: hout[6][1536][hp] f32 (~8.85 MB at hp=240)
  const size_t HN = (size_t)NL * NSLOT;
  const int hp = (ws_size >= HN * 240 * 4) ? 240 : 234;
  float* hout = (float*)d_ws;

  init_kernel<<<2048, 256, 0, stream>>>((unsigned*)hout, hp);
  lstm_pipe<<<NL * GPL + NHEAD, BLOCK, 0, stream>>>(
      X, Wih0, Wih, Whh, bih, bhh, Wl, bl, (float*)d_out, hout, hp / 2);
}

// Round 12
// 2592.069 us; speedup vs baseline: 1.8515x; 1.0654x over previous
//
#include <hip/hip_runtime.h>

// ---------------- problem constants ----------------
#define HND    233
#define NL     6
#define GPL    15             // WGs per layer
#define UPW    16             // units per WG (15*16 = 240 >= 233)
#define ROWS   64             // gate rows per WG
#define TSTEPS 16
#define FSTEPS 96
#define NSLOT  (TSTEPS*FSTEPS)
#define CDIM   12
#define G4H    (4*HND)        // 932
#define HP     240            // h-section offset in vin row; hout stride target
#define RL     480            // vin row: [x 240 | h 240]
#define NTICK  (6*95+15+1)    // 586 wavefront ticks (critical-path optimal)
#define NHEAD  3
#define BLOCK  256
#define NWORD  234            // u64 words per stream (117 x + 117 h)
#define AG     __HIP_MEMORY_SCOPE_AGENT
#define SENT   0x7FBADBADu    // NaN pattern: unreachable by real data
#define PLIM   (1L << 18)     // poll bail (loud NaN, no hang)

typedef unsigned long long u64;

__device__ __forceinline__ float sigf(float x) { return 1.f / (1.f + expf(-x)); }
__device__ __forceinline__ bool rdy(u64 v) {
  return ((unsigned)v != SENT) && ((unsigned)(v >> 32) != SENT);
}

// Active (f,t) streams at tick m: t = m - 6f in [0,15]; ns <= 3.
__device__ __forceinline__ int build(int m, int* fl, int* tl) {
  const int fh0 = m / 6;
  const int f_hi = (fh0 > 95) ? 95 : fh0;
  const int f_lo = (m < 10) ? 0 : (m - 10) / 6;
  #pragma unroll
  for (int k = 0; k < 3; ++k) { fl[k] = f_lo + k; tl[k] = m - 6 * (f_lo + k); }
  return f_hi - f_lo + 1;
}

// Re-poison hout: data dwords -> SENT, pad dwords -> 0.
__global__ void init_kernel(unsigned* __restrict__ hout, int hp) {
  size_t i = (size_t)blockIdx.x * blockDim.x + threadIdx.x;
  size_t stride = (size_t)gridDim.x * blockDim.x;
  const size_t nh = (size_t)NL * NSLOT * hp;
  for (size_t k = i; k < nh; k += stride) hout[k] = ((int)(k % hp) < HND) ? SENT : 0u;
}

// grid: NL*GPL layer WGs + NHEAD head WGs, 256 threads (4 waves).
// Protocol: MALL relaxed atomics only; consumers poll the DATA itself.
// ONE barrier per tick: [stage into vin[p] -> barrier -> per-wave matvec
// (in-wave shfl reduce) -> per-wave cell -> immediate publish; own-slice h
// written straight into vin[p^1] for next tick]. Disjointness: stage(m+1)
// writes vin[p^1] {x-section, non-own h, t==0 zeros}; cell(m) writes
// vin[p^1] {own h slice} -- no overlap; matvec(m) reads vin[p] only, and the
// tick-(m+1) barrier orders cell(m) writes before matvec(m+1) reads.
__global__ void __launch_bounds__(BLOCK, 1) lstm_pipe(
    const float* __restrict__ X,
    const float* __restrict__ Wih0, const float* __restrict__ Wih,
    const float* __restrict__ Whh,  const float* __restrict__ bih,
    const float* __restrict__ bhh,  const float* __restrict__ Wl,
    const float* __restrict__ bl,   float* __restrict__ out,
    float* __restrict__ hout, int hps) {
  __shared__ float vin[2][3][RL];       // parity x stream-slot x [x|h]
  __shared__ float bias[ROWS];
  __shared__ float foldb[ROWS];         // l0: Wih0 @ bl (f>=1 only)
  __shared__ float wih0s[ROWS][CDIM];   // l0: raw Wih0 rows (f==0 correction)
  __shared__ float xs[TSTEPS][CDIM];    // l0: f==0 seed = X[t][95][:]
  __shared__ float wlh[CDIM][HP];       // Wl padded (l0 fold + head dot)

  const int tid = threadIdx.x;
  const int bid = blockIdx.x;
  u64* hu = (u64*)hout;

  if (bid >= NL * GPL) {
    // ---------------- head WGs: out[t][f][:] = Wl.h5(f,t)+bl, f%3==hid ----
    const int hid = bid - NL * GPL;
    for (int i = tid; i < CDIM * HP; i += BLOCK) {
      int rr = i / HP, k = i % HP;
      ((float*)wlh)[i] = (k < HND) ? Wl[rr * HND + k] : 0.f;
    }
    for (int i = tid; i < RL; i += BLOCK) vin[0][0][i] = 0.f;
    __syncthreads();
    for (int f = hid; f < FSTEPS; f += NHEAD) {
      for (int t = 0; t < TSTEPS; ++t) {
        if (tid < 117) {
          const u64* src = hu + ((size_t)5 * NSLOT + 16 * f + t) * hps + tid;
          u64 v; long gd = 0;
          for (;;) {
            v = __hip_atomic_load(src, __ATOMIC_RELAXED, AG);
            if (rdy(v)) break;
            if (++gd > PLIM) break;
            if (gd > 4) __builtin_amdgcn_s_sleep(1);
          }
          *(u64*)&vin[0][0][2 * tid] = v;
        }
        __syncthreads();
        if (tid < 48) {
          int rr = tid >> 2, q = tid & 3;
          const float4* wr = (const float4*)&wlh[rr][0];
          const float4* hv = (const float4*)&vin[0][0][0];
          float a = 0.f;
          #pragma unroll
          for (int c = 0; c < 15; ++c) {
            float4 x0 = wr[q * 15 + c], y0 = hv[q * 15 + c];
            a = fmaf(x0.w, y0.w, fmaf(x0.z, y0.z, fmaf(x0.y, y0.y, fmaf(x0.x, y0.x, a))));
          }
          a += __shfl_xor(a, 1);
          a += __shfl_xor(a, 2);
          if (q == 0) out[((size_t)t * FSTEPS + f) * CDIM + rr] = a + bl[rr];
        }
        __syncthreads();
      }
    }
    return;
  }

  // ---------------- layer workgroup ----------------
  const int l = bid / GPL, g = bid % GPL;
  const int j0 = g * UPW;
  const int U = min(UPW, HND - j0);            // last WG: 9 units
  const int wave = tid >> 6, ln = tid & 63;
  const int rr = ln & 15, q = ln >> 4;         // in-wave: 16 rows x 4 quarters
  const int row = wave * 16 + rr;              // 0..63
  const int u = row >> 2, gt = row & 3;
  const int grow = gt * HND + j0 + u;
  const bool rowok = (u < U);

  // ---- small LDS tables
  if (l == 0) {
    for (int i = tid; i < CDIM * HP; i += BLOCK) {
      int r2 = i / HP, k = i % HP;
      ((float*)wlh)[i] = (k < HND) ? Wl[r2 * HND + k] : 0.f;
    }
    for (int i = tid; i < ROWS * CDIM; i += BLOCK) {
      int r2 = i / CDIM, c = i % CDIM;
      int uu = r2 >> 2, g2 = r2 & 3;
      wih0s[r2][c] = (uu < U) ? Wih0[(g2 * HND + j0 + uu) * CDIM + c] : 0.f;
    }
    for (int i = tid; i < TSTEPS * CDIM; i += BLOCK)
      xs[i / CDIM][i % CDIM] = X[((size_t)(i / CDIM) * 96 + 95) * CDIM + (i % CDIM)];
  }
  for (int i = tid; i < 2 * 3 * RL; i += BLOCK) ((float*)vin)[i] = 0.f;
  __syncthreads();

  // ---- weights into REGISTERS (120-float slice; statically indexed)
  // row layout: [x-weights 240 | Whh 240]; l0 x-weights = Wih0 @ Wl.
  float4 w4[30];
  const float* wihl = Wih + (size_t)(l - 1) * G4H * HND;
  const float* whhl = Whh + (size_t)l * G4H * HND;
  #pragma unroll
  for (int j = 0; j < 30; ++j) {
    float e[4];
    #pragma unroll
    for (int ee = 0; ee < 4; ++ee) {
      const int idx = (q * 30 + j) * 4 + ee;
      float v = 0.f;
      if (rowok) {
        if (idx < HND) {
          if (l == 0) {
            float acc = 0.f;
            #pragma unroll
            for (int c = 0; c < CDIM; ++c) acc = fmaf(wih0s[row][c], wlh[c][idx], acc);
            v = acc;
          } else {
            v = wihl[(size_t)grow * HND + idx];
          }
        } else if (idx >= HP && idx < HP + HND) {
          v = whhl[(size_t)grow * HND + (idx - HP)];
        }
      }
      e[ee] = v;
    }
    w4[j] = make_float4(e[0], e[1], e[2], e[3]);
  }
  if (tid < ROWS) {
    float b = 0.f, fb = 0.f;
    if ((tid >> 2) < U) {
      const int gr2 = (tid & 3) * HND + j0 + (tid >> 2);
      b = bih[l * G4H + gr2] + bhh[l * G4H + gr2];
      if (l == 0) {   // Wih0 @ bl: folded-token path only (f>=1)
        #pragma unroll
        for (int c = 0; c < CDIM; ++c) fb = fmaf(wih0s[tid][c], bl[c], fb);
      }
    }
    bias[tid] = b;
    foldb[tid] = fb;
  }
  __syncthreads();

  // ---- per-lane cell state (named regs, rule #20) for units 4*wave + (ln&3)
  float cs0 = 0.f, cs1 = 0.f, cs2 = 0.f;
  const int v4 = ln & 3;
  const int ug = j0 + 4 * wave + v4;           // global unit (lanes 0..3)
  int fl[3], tl[3];

  for (int m = 0; m < NTICK; ++m) {
    const int ns = build(m, fl, tl);
    const int p = m & 1;

    // ---- STAGE into vin[p]: poll the data itself (<=3 words/thread)
    const u64 *s0 = nullptr, *s1 = nullptr, *s2 = nullptr;
    u64 *d0 = nullptr, *d1 = nullptr, *d2 = nullptr;

    auto setup = [&](int w, const u64*& sp, u64*& dp) {
      const int k = w / NWORD;
      if (k >= ns) return;
      const int f = fl[k], t = tl[k];
      const int o = w - k * NWORD;
      if (o < 117) {                       // x-section word
        float* dst = &vin[p][k][2 * o];
        if (l == 0 && f == 0) { dst[0] = 0.f; dst[1] = 0.f; return; }
        sp = (l == 0)
           ? hu + ((size_t)5 * NSLOT + 16 * (f - 1) + t) * hps + o
           : hu + ((size_t)(l - 1) * NSLOT + 16 * f + t) * hps + o;
        dp = (u64*)dst;
      } else {                             // h-section word
        const int jj = o - 117;
        float* dst = &vin[p][k][HP + 2 * jj];
        if (t == 0) { dst[0] = 0.f; dst[1] = 0.f; return; }
        if ((jj >> 3) == g) return;        // own slice: cell(m-1) wrote it
        sp = hu + ((size_t)l * NSLOT + 16 * f + (t - 1)) * hps + jj;
        dp = (u64*)dst;
      }
    };
    setup(tid, s0, d0);
    setup(tid + 256, s1, d1);
    if (tid + 512 < 3 * NWORD) setup(tid + 512, s2, d2);

    long gd = 0;
    while (s0 || s1 || s2) {
      if (s0) { u64 v = __hip_atomic_load(s0, __ATOMIC_RELAXED, AG);
                if (rdy(v)) { *d0 = v; s0 = nullptr; } }
      if (s1) { u64 v = __hip_atomic_load(s1, __ATOMIC_RELAXED, AG);
                if (rdy(v)) { *d1 = v; s1 = nullptr; } }
      if (s2) { u64 v = __hip_atomic_load(s2, __ATOMIC_RELAXED, AG);
                if (rdy(v)) { *d2 = v; s2 = nullptr; } }
      if (++gd > PLIM) break;              // bail loudly (NaN), no hang
      if (gd > 8) __builtin_amdgcn_s_sleep(1);
    }
    __syncthreads();                       // the ONLY barrier per tick

    // ---- MATVEC: single pass over weights, 3 accumulators
    const float4* va = (const float4*)&vin[p][0][0];
    const float4* vb = (const float4*)&vin[p][1][0];
    const float4* vc = (const float4*)&vin[p][2][0];
    float a0 = 0.f, a1 = 0.f, a2 = 0.f;
    #pragma unroll
    for (int j = 0; j < 30; ++j) {
      const int c = q * 30 + j;
      const float4 wv = w4[j];
      const float4 y0 = va[c];
      const float4 y1 = vb[c];
      const float4 y2 = vc[c];
      a0 = fmaf(wv.x, y0.x, fmaf(wv.y, y0.y, fmaf(wv.z, y0.z, fmaf(wv.w, y0.w, a0))));
      a1 = fmaf(wv.x, y1.x, fmaf(wv.y, y1.y, fmaf(wv.z, y1.z, fmaf(wv.w, y1.w, a1))));
      a2 = fmaf(wv.x, y2.x, fmaf(wv.y, y2.y, fmaf(wv.z, y2.z, fmaf(wv.w, y2.w, a2))));
    }
    // in-wave reduce over the 4 k-quarters (lanes 16 and 32 apart)
    a0 += __shfl_xor(a0, 16); a0 += __shfl_xor(a0, 32);
    a1 += __shfl_xor(a1, 16); a1 += __shfl_xor(a1, 32);
    a2 += __shfl_xor(a2, 16); a2 += __shfl_xor(a2, 32);
    const float bv = bias[row];
    a0 += bv; a1 += bv; a2 += bv;

    // ---- CELL + immediate publish, per wave (no cross-wave barrier)
    const int fl2next = ((m + 1) < 10) ? 0 : (m + 1 - 10) / 6;
    #pragma unroll
    for (int k = 0; k < 3; ++k) {
      if (k >= ns) break;
      const int f = fl[k], t = tl[k];
      const int b3 = f % 3;
      const float gv = (k == 0) ? a0 : (k == 1) ? a1 : a2;
      float gg[4];
      #pragma unroll
      for (int g2 = 0; g2 < 4; ++g2) gg[g2] = __shfl(gv, 4 * v4 + g2);
      float hn = 0.f;
      if (ln < 4 && ug < HND) {
        const int rowc = 16 * wave + 4 * v4;
        if (l == 0) {
          if (f == 0) {                    // x = raw 12-dim seed
            #pragma unroll
            for (int g2 = 0; g2 < 4; ++g2) {
              float s = gg[g2];
              #pragma unroll
              for (int c = 0; c < CDIM; ++c) s = fmaf(wih0s[rowc + g2][c], xs[t][c], s);
              gg[g2] = s;
            }
          } else {
            #pragma unroll
            for (int g2 = 0; g2 < 4; ++g2) gg[g2] += foldb[rowc + g2];
          }
        }
        const float cp = (t == 0) ? 0.f : (b3 == 0 ? cs0 : (b3 == 1 ? cs1 : cs2));
        const float cn = sigf(gg[1]) * cp + sigf(gg[0]) * tanhf(gg[2]);
        hn = sigf(gg[3]) * tanhf(cn);
        if (b3 == 0) cs0 = cn; else if (b3 == 1) cs1 = cn; else cs2 = cn;
        if (t < 15)                        // own slice for next tick
          vin[p ^ 1][f - fl2next][HP + ug] = hn;
      }
      const float lo = __shfl(hn, 2 * ln);
      const float hi = __shfl(hn, 2 * ln + 1);
      const int pu = j0 + 4 * wave + 2 * ln;  // pair start unit (lanes 0,1)
      if (ln < 2 && pu < HND) {
        const u64 pv = ((u64)__float_as_uint(hi) << 32) | (u64)__float_as_uint(lo);
        __hip_atomic_store(hu + ((size_t)l * NSLOT + 16 * f + t) * hps + (pu >> 1),
                           pv, __ATOMIC_RELAXED, AG);
      }
    }
    // no second barrier: see disjointness argument above.
  }
}

extern "C" void kernel_launch(void* const* d_in, const int* in_sizes, int n_in,
                              void* d_out, int out_size, void* d_ws, size_t ws_size,
                              hipStream_t stream) {
  const float* X    = (const float*)d_in[0];
  const float* Wih0 = (const float*)d_in[1];
  const float* Wih  = (const float*)d_in[2];
  const float* Whh  = (const float*)d_in[3];
  const float* bih  = (const float*)d_in[4];
  const float* bhh  = (const float*)d_in[5];
  const float* Wl   = (const float*)d_in[6];
  const float* bl   = (const float*)d_in[7];

  // workspace: hout[6][1536][hp] f32 (~8.85 MB at hp=240)
  const size_t HN = (size_t)NL * NSLOT;
  const int hp = (ws_size >= HN * 240 * 4) ? 240 : 234;
  float* hout = (float*)d_ws;

  init_kernel<<<2048, 256, 0, stream>>>((unsigned*)hout, hp);
  lstm_pipe<<<NL * GPL + NHEAD, BLOCK, 0, stream>>>(
      X, Wih0, Wih, Whh, bih, bhh, Wl, bl, (float*)d_out, hout, hp / 2);
}